// Round 2
// baseline (527.802 us; speedup 1.0000x reference)
//
#include <hip/hip_runtime.h>

#define E_TOTAL 600000
#define NTILES (E_TOTAL / 64)  // 9375
#define NB 768                 // persistent blocks: 3 resident per CU x 256 CUs
#define LDH 264  // LDS row stride in shorts; 528 B -> balanced banks, 16B aligned

typedef __attribute__((ext_vector_type(8))) short short8;
typedef __attribute__((ext_vector_type(4))) float f32x4;

__device__ __forceinline__ unsigned f2bf_u(float f) {
  union { float f; unsigned u; } v; v.f = f;
  return (v.u + 0x7fffu + ((v.u >> 16) & 1u)) >> 16;  // RNE
}

// LDS-only barrier: drain ds ops, do NOT drain vmcnt (global loads stay in flight).
__device__ __forceinline__ void ldsBarrier() {
  asm volatile("s_waitcnt lgkmcnt(0)\n\ts_barrier" ::: "memory");
}

// ---- weight prep: tiled transpose+cast. W1[k][n]->W1t[n][k] bf16, W2 likewise ----
__global__ __launch_bounds__(256) void prep_weights(
    const float* __restrict__ W1, const float* __restrict__ W2,
    unsigned short* __restrict__ W1t, unsigned short* __restrict__ W2t) {
  __shared__ float t[32][33];
  int bid = blockIdx.x;
  const float* S; unsigned short* D; int k0, n0, N;
  if (bid < 64) { S = W1; D = W1t; N = 256; k0 = (bid >> 3) * 32; n0 = (bid & 7) * 32; }
  else { bid -= 64; S = W2; D = W2t; N = 64; k0 = (bid >> 1) * 32; n0 = (bid & 1) * 32; }
  int tx = threadIdx.x & 31, ty = threadIdx.x >> 5;
#pragma unroll
  for (int i = 0; i < 32; i += 8) t[ty + i][tx] = S[(k0 + ty + i) * N + n0 + tx];
  __syncthreads();
#pragma unroll
  for (int i = 0; i < 32; i += 8)
    D[(n0 + ty + i) * 256 + k0 + tx] = (unsigned short)f2bf_u(t[tx][ty + i]);
}

// ---- fused edge MLP: persistent blocks, cross-tile software pipeline ----
// Register-pressure-safe schedule: gather(t+NB) is issued in the hidden phase
// AFTER the pack kills acc[][] (peak regs ~140, no spill), stays in flight
// across bar3 + phase2 + bar4 (vmcnt untouched by ldsBarrier), and is
// converted+stored to LDS right before bar1'. vmem issue order per iter:
//   [phase1: wa chain] [w2f] [gather] [idx] -> phase2 waits w2f via vmcnt(24),
// leaving gather+idx in flight.
__global__ __launch_bounds__(256, 3) void edge_mlp(
    const float* __restrict__ x, const int* __restrict__ ei,
    const unsigned short* __restrict__ W1t, const unsigned short* __restrict__ W2t,
    const float* __restrict__ b1, const float* __restrict__ b2,
    float* __restrict__ out) {
  __shared__ __align__(16) unsigned short lds[64 * LDH];  // feat tile, reused as hidden
  __shared__ float ldsb1[256];
  __shared__ float ldsb2[64];

  const int tid = threadIdx.x;
  const int* __restrict__ srcI = ei;
  const int* __restrict__ dstI = ei + E_TOTAL;

  const int lane = tid & 63;
  const int w = tid >> 6;    // wave 0..3
  const int m = lane & 15;
  const int q = lane >> 4;

  const int kb = (tid & 31) * 8;        // 0..248, fixed per thread
  const int xo = kb & 127;
  const int e0 = tid >> 5;              // 0..7
  const int* __restrict__ idxp = (kb < 128) ? srcI : dstI;

  int w1off[4];
#pragma unroll
  for (int nt = 0; nt < 4; ++nt) w1off[nt] = ((w * 4 + nt) * 16 + m) * 256 + q * 8;
  const int w2off = (w * 16 + m) * 256 + q * 8;

  int t = blockIdx.x;

  // ---- prologue: idx(t); biases; gather(t); idx(t+NB); feat(t) -> LDS ----
  int nxt[8];
#pragma unroll
  for (int i = 0; i < 8; ++i) nxt[i] = idxp[t * 64 + e0 + 8 * i];

  float b2tmp = 0.f;
  if (tid < 64) b2tmp = b2[tid];
  float b1tmp = b1[tid];

  f32x4 g0[8], g1[8];
#pragma unroll
  for (int i = 0; i < 8; ++i) {
    const float* p = x + (size_t)((nxt[i] << 7) + xo);
    g0[i] = *(const f32x4*)p;
    g1[i] = *(const f32x4*)(p + 4);
  }

  if (t + NB < NTILES) {
#pragma unroll
    for (int i = 0; i < 8; ++i) nxt[i] = idxp[(t + NB) * 64 + e0 + 8 * i];
  }

  ldsb1[tid] = b1tmp;
  if (tid < 64) ldsb2[tid] = b2tmp;

#pragma unroll
  for (int i = 0; i < 8; ++i) {
    short8 s;
#pragma unroll
    for (int j = 0; j < 4; ++j) {
      s[j]     = (short)f2bf_u(g0[i][j]);
      s[4 + j] = (short)f2bf_u(g1[i][j]);
    }
    *(short8*)&lds[(e0 + 8 * i) * LDH + kb] = s;
  }

  short8 wa[2][4];
#pragma unroll
  for (int nt = 0; nt < 4; ++nt) wa[0][nt] = *(const short8*)&W1t[w1off[nt]];

  ldsBarrier();  // feat(t) visible

  for (; t < NTILES; t += NB) {
    const bool hn = (t + NB) < NTILES;

    // ---- phase 1: D[n1][e] = sum_k W1t[n1][k] * feat[e][k] ----
    f32x4 acc[4][4];
#pragma unroll
    for (int nt = 0; nt < 4; ++nt)
#pragma unroll
      for (int mt = 0; mt < 4; ++mt) acc[nt][mt] = (f32x4){0.f, 0.f, 0.f, 0.f};

#pragma unroll
    for (int kk = 0; kk < 8; ++kk) {
      const int cur = kk & 1, nx = cur ^ 1;
      if (kk < 7) {
#pragma unroll
        for (int nt = 0; nt < 4; ++nt)
          wa[nx][nt] = *(const short8*)&W1t[w1off[nt] + (kk + 1) * 32];
      }
      short8 f[4];
#pragma unroll
      for (int mt = 0; mt < 4; ++mt)
        f[mt] = *(const short8*)&lds[(mt * 16 + m) * LDH + kk * 32 + q * 8];
#pragma unroll
      for (int nt = 0; nt < 4; ++nt)
#pragma unroll
        for (int mt = 0; mt < 4; ++mt)
          acc[nt][mt] = __builtin_amdgcn_mfma_f32_16x16x32_bf16(wa[cur][nt], f[mt], acc[nt][mt], 0, 0, 0);
    }

    ldsBarrier();  // bar2: feat reads done; safe to overwrite with hidden

    // ---- hidden phase ----
    // (a) W2 frags FIRST (must be older than the gather in the vmcnt queue)
    short8 w2f[8];
#pragma unroll
    for (int j = 0; j < 8; ++j) w2f[j] = *(const short8*)&W2t[w2off + j * 32];

    // (b) bias + relu + packed hidden write -> kills acc before gather regs go live
    f32x4 bias[4];
#pragma unroll
    for (int nt = 0; nt < 4; ++nt) bias[nt] = *(const f32x4*)&ldsb1[w * 64 + nt * 16 + q * 4];
#pragma unroll
    for (int nt = 0; nt < 4; ++nt)
#pragma unroll
      for (int mt = 0; mt < 4; ++mt) {
        float h0 = fmaxf(acc[nt][mt][0] + bias[nt][0], 0.f);
        float h1 = fmaxf(acc[nt][mt][1] + bias[nt][1], 0.f);
        float h2 = fmaxf(acc[nt][mt][2] + bias[nt][2], 0.f);
        float h3 = fmaxf(acc[nt][mt][3] + bias[nt][3], 0.f);
        uint2 pk;
        pk.x = f2bf_u(h0) | (f2bf_u(h1) << 16);
        pk.y = f2bf_u(h2) | (f2bf_u(h3) << 16);
        *(uint2*)&lds[(mt * 16 + m) * LDH + w * 64 + nt * 16 + q * 4] = pk;
      }

    // (c) issue gather(t+NB): in flight across bar3 + phase2 + bar4
    if (hn) {
#pragma unroll
      for (int i = 0; i < 8; ++i) {
        const float* p = x + (size_t)((nxt[i] << 7) + xo);
        g0[i] = *(const f32x4*)p;
        g1[i] = *(const f32x4*)(p + 4);
      }
    }

    // (d) idx(t+2NB), youngest in queue
    if (t + 2 * NB < NTILES) {
#pragma unroll
      for (int i = 0; i < 8; ++i) nxt[i] = idxp[(t + 2 * NB) * 64 + e0 + 8 * i];
    }

    ldsBarrier();  // bar3: hidden visible

    // ---- phase 2: D[n2][e] = sum_k W2t[n2][k] * hidden[e][k] ----
    f32x4 acc2[4];
#pragma unroll
    for (int mt = 0; mt < 4; ++mt) acc2[mt] = (f32x4){0.f, 0.f, 0.f, 0.f};
#pragma unroll
    for (int kk = 0; kk < 8; ++kk) {
#pragma unroll
      for (int mt = 0; mt < 4; ++mt) {
        short8 h = *(const short8*)&lds[(mt * 16 + m) * LDH + kk * 32 + q * 8];
        acc2[mt] = __builtin_amdgcn_mfma_f32_16x16x32_bf16(w2f[kk], h, acc2[mt], 0, 0, 0);
      }
    }

    f32x4 b2v = *(const f32x4*)&ldsb2[w * 16 + q * 4];
#pragma unroll
    for (int mt = 0; mt < 4; ++mt) {
      f32x4 o;
#pragma unroll
      for (int r = 0; r < 4; ++r) o[r] = acc2[mt][r] + b2v[r];
      *(f32x4*)&out[(t * 64 + mt * 16 + m) * 64 + w * 16 + q * 4] = o;
    }

    ldsBarrier();  // bar4: phase2 LDS reads done on all waves; feat region free

    // ---- convert + store feat(t+NB) (waits only the gather), wa0 prefetch ----
    if (hn) {
#pragma unroll
      for (int i = 0; i < 8; ++i) {
        short8 s;
#pragma unroll
        for (int j = 0; j < 4; ++j) {
          s[j]     = (short)f2bf_u(g0[i][j]);
          s[4 + j] = (short)f2bf_u(g1[i][j]);
        }
        *(short8*)&lds[(e0 + 8 * i) * LDH + kb] = s;
      }
#pragma unroll
      for (int nt = 0; nt < 4; ++nt) wa[0][nt] = *(const short8*)&W1t[w1off[nt]];
    }
    ldsBarrier();  // bar1': feat(t+NB) visible for next iteration
  }
}

extern "C" void kernel_launch(void* const* d_in, const int* in_sizes, int n_in,
                              void* d_out, int out_size, void* d_ws, size_t ws_size,
                              hipStream_t stream) {
  const float* x  = (const float*)d_in[0];
  const int*   ei = (const int*)d_in[1];
  const float* W1 = (const float*)d_in[2];
  const float* b1 = (const float*)d_in[3];
  const float* W2 = (const float*)d_in[4];
  const float* b2 = (const float*)d_in[5];
  float* out = (float*)d_out;

  unsigned short* W1t = (unsigned short*)d_ws;   // 256*256 bf16
  unsigned short* W2t = W1t + 256 * 256;         // 64*256 bf16

  prep_weights<<<80, 256, 0, stream>>>(W1, W2, W1t, W2t);
  edge_mlp<<<NB, 256, 0, stream>>>(x, ei, W1t, W2t, b1, b2, out);
}

// Round 3
// 328.021 us; speedup vs baseline: 1.6090x; 1.6090x over previous
//
#include <hip/hip_runtime.h>

#define E_TOTAL 600000
#define NT2 4688   // ceil(600000/128); last tile is half (guarded)
#define LDH 264    // LDS row stride in shorts; 528 B -> stride 4 banks, 16B aligned

typedef __attribute__((ext_vector_type(8))) short short8;
typedef __attribute__((ext_vector_type(4))) short short4v;
typedef __attribute__((ext_vector_type(4))) float f32x4;

__device__ __forceinline__ unsigned f2bf_u(float f) {
  union { float f; unsigned u; } v; v.f = f;
  return (v.u + 0x7fffu + ((v.u >> 16) & 1u)) >> 16;  // RNE
}

// LDS-only barrier: drain ds ops, do NOT drain vmcnt.
__device__ __forceinline__ void ldsBarrier() {
  asm volatile("s_waitcnt lgkmcnt(0)\n\ts_barrier" ::: "memory");
}

// ---- weight prep: tiled transpose+cast. W1[k][n]->W1t[n][k] bf16, W2 likewise ----
__global__ __launch_bounds__(256) void prep_weights(
    const float* __restrict__ W1, const float* __restrict__ W2,
    unsigned short* __restrict__ W1t, unsigned short* __restrict__ W2t) {
  __shared__ float t[32][33];
  int bid = blockIdx.x;
  const float* S; unsigned short* D; int k0, n0, N;
  if (bid < 64) { S = W1; D = W1t; N = 256; k0 = (bid >> 3) * 32; n0 = (bid & 7) * 32; }
  else { bid -= 64; S = W2; D = W2t; N = 64; k0 = (bid >> 1) * 32; n0 = (bid & 1) * 32; }
  int tx = threadIdx.x & 31, ty = threadIdx.x >> 5;
#pragma unroll
  for (int i = 0; i < 32; i += 8) t[ty + i][tx] = S[(k0 + ty + i) * N + n0 + tx];
  __syncthreads();
#pragma unroll
  for (int i = 0; i < 32; i += 8)
    D[(n0 + ty + i) * 256 + k0 + tx] = (unsigned short)f2bf_u(t[tx][ty + i]);
}

// ---- x -> bf16 pre-convert: halves gather lines + footprint (12.8 MB, L2-friendly) ----
__global__ __launch_bounds__(256) void prep_x(const float* __restrict__ x,
                                              unsigned short* __restrict__ xb) {
  int i = (blockIdx.x * 256 + threadIdx.x) * 4;  // grid covers exactly 6.4M elems
  f32x4 v = *(const f32x4*)(x + i);
  short4v s;
#pragma unroll
  for (int j = 0; j < 4; ++j) s[j] = (short)f2bf_u(v[j]);
  *(short4v*)(xb + i) = s;
}

// ---- fused edge MLP: 128-edge tiles, round-0 schedule (no cross-tile pipeline) ----
// Rationale: kernel is L1-miss/request-throughput bound. 128-edge tiles amortize
// each wave's 32KB W1t stream over 2x edges; bf16 x halves gather lines.
// acc[4][8]=128 VGPRs needs the 256-VGPR cap of (256,2); LDS 68.9KB -> 2 blocks/CU.
__global__ __launch_bounds__(256, 2) void edge_mlp(
    const unsigned short* __restrict__ xb, const int* __restrict__ ei,
    const unsigned short* __restrict__ W1t, const unsigned short* __restrict__ W2t,
    const float* __restrict__ b1, const float* __restrict__ b2,
    float* __restrict__ out) {
  __shared__ __align__(16) unsigned short lds[128 * LDH];  // feat tile, reused as hidden
  __shared__ float ldsb1[256];
  __shared__ float ldsb2[64];

  const int tid = threadIdx.x;
  const int base = blockIdx.x * 128;
  const int* __restrict__ srcI = ei;
  const int* __restrict__ dstI = ei + E_TOTAL;

  const int lane = tid & 63;
  const int w = tid >> 6;    // wave 0..3
  const int m = lane & 15;
  const int q = lane >> 4;

  const int kb = (tid & 31) * 8;        // 0..248: k-chunk this thread stages
  const int xo = kb & 127;              // offset within node row (bf16 elems)
  const int e0 = tid >> 5;              // 0..7
  const int* __restrict__ idxp = (kb < 128) ? srcI : dstI;

  // ---- idx loads (clamped for the half tail tile) ----
  int nodes[16];
#pragma unroll
  for (int i = 0; i < 16; ++i) {
    int e = base + e0 + 8 * i;
    nodes[i] = idxp[e < E_TOTAL ? e : (E_TOTAL - 1)];
  }

  float b2tmp = 0.f;
  if (tid < 64) b2tmp = b2[tid];
  float b1tmp = b1[tid];
  ldsb1[tid] = b1tmp;
  if (tid < 64) ldsb2[tid] = b2tmp;

  // ---- bf16 gather -> LDS (no convert; 16B/lane, 4 lines per node row) ----
#pragma unroll
  for (int i = 0; i < 16; ++i) {
    const unsigned short* p = xb + nodes[i] * 128 + xo;
    short8 v = *(const short8*)p;
    *(short8*)&lds[(e0 + 8 * i) * LDH + kb] = v;
  }

  int w1off[4];
#pragma unroll
  for (int nt = 0; nt < 4; ++nt) w1off[nt] = ((w * 4 + nt) * 16 + m) * 256 + q * 8;
  const int w2off = (w * 16 + m) * 256 + q * 8;

  short8 wa[2][4];
#pragma unroll
  for (int nt = 0; nt < 4; ++nt) wa[0][nt] = *(const short8*)&W1t[w1off[nt]];

  ldsBarrier();  // feat visible

  // ---- phase 1: D[n1][e] = sum_k W1t[n1][k] * feat[e][k]  (8 edge-frags/wave) ----
  f32x4 acc[4][8];
#pragma unroll
  for (int nt = 0; nt < 4; ++nt)
#pragma unroll
    for (int mt = 0; mt < 8; ++mt) acc[nt][mt] = (f32x4){0.f, 0.f, 0.f, 0.f};

#pragma unroll
  for (int kk = 0; kk < 8; ++kk) {
    const int cur = kk & 1, nx = cur ^ 1;
    if (kk < 7) {
#pragma unroll
      for (int nt = 0; nt < 4; ++nt)
        wa[nx][nt] = *(const short8*)&W1t[w1off[nt] + (kk + 1) * 32];
    }
    short8 f[8];
#pragma unroll
    for (int mt = 0; mt < 8; ++mt)
      f[mt] = *(const short8*)&lds[(mt * 16 + m) * LDH + kk * 32 + q * 8];
#pragma unroll
    for (int nt = 0; nt < 4; ++nt)
#pragma unroll
      for (int mt = 0; mt < 8; ++mt)
        acc[nt][mt] = __builtin_amdgcn_mfma_f32_16x16x32_bf16(wa[cur][nt], f[mt], acc[nt][mt], 0, 0, 0);
  }

  ldsBarrier();  // feat reads done; safe to overwrite with hidden

  // ---- hidden phase: w2f loads (covered by pack VALU), bias+relu+pack ----
  short8 w2f[8];
#pragma unroll
  for (int j = 0; j < 8; ++j) w2f[j] = *(const short8*)&W2t[w2off + j * 32];

  f32x4 bias[4];
#pragma unroll
  for (int nt = 0; nt < 4; ++nt) bias[nt] = *(const f32x4*)&ldsb1[w * 64 + nt * 16 + q * 4];
#pragma unroll
  for (int nt = 0; nt < 4; ++nt)
#pragma unroll
    for (int mt = 0; mt < 8; ++mt) {
      float h0 = fmaxf(acc[nt][mt][0] + bias[nt][0], 0.f);
      float h1 = fmaxf(acc[nt][mt][1] + bias[nt][1], 0.f);
      float h2 = fmaxf(acc[nt][mt][2] + bias[nt][2], 0.f);
      float h3 = fmaxf(acc[nt][mt][3] + bias[nt][3], 0.f);
      uint2 pk;
      pk.x = f2bf_u(h0) | (f2bf_u(h1) << 16);
      pk.y = f2bf_u(h2) | (f2bf_u(h3) << 16);
      *(uint2*)&lds[(mt * 16 + m) * LDH + w * 64 + nt * 16 + q * 4] = pk;
    }

  ldsBarrier();  // hidden visible

  // ---- phase 2: D[n2][e] = sum_k W2t[n2][k] * hidden[e][k] ----
  f32x4 acc2[8];
#pragma unroll
  for (int mt = 0; mt < 8; ++mt) acc2[mt] = (f32x4){0.f, 0.f, 0.f, 0.f};
#pragma unroll
  for (int kk = 0; kk < 8; ++kk) {
#pragma unroll
    for (int mt = 0; mt < 8; ++mt) {
      short8 h = *(const short8*)&lds[(mt * 16 + m) * LDH + kk * 32 + q * 8];
      acc2[mt] = __builtin_amdgcn_mfma_f32_16x16x32_bf16(w2f[kk], h, acc2[mt], 0, 0, 0);
    }
  }

  f32x4 b2v = *(const f32x4*)&ldsb2[w * 16 + q * 4];
#pragma unroll
  for (int mt = 0; mt < 8; ++mt) {
    int e = base + mt * 16 + m;
    if (e < E_TOTAL) {
      f32x4 o;
#pragma unroll
      for (int r = 0; r < 4; ++r) o[r] = acc2[mt][r] + b2v[r];
      *(f32x4*)&out[e * 64 + w * 16 + q * 4] = o;
    }
  }
}

extern "C" void kernel_launch(void* const* d_in, const int* in_sizes, int n_in,
                              void* d_out, int out_size, void* d_ws, size_t ws_size,
                              hipStream_t stream) {
  const float* x  = (const float*)d_in[0];
  const int*   ei = (const int*)d_in[1];
  const float* W1 = (const float*)d_in[2];
  const float* b1 = (const float*)d_in[3];
  const float* W2 = (const float*)d_in[4];
  const float* b2 = (const float*)d_in[5];
  float* out = (float*)d_out;

  unsigned short* W1t = (unsigned short*)d_ws;   // 256*256 bf16
  unsigned short* W2t = W1t + 256 * 256;         // 64*256 bf16
  unsigned short* xb  = W2t + 64 * 256;          // 50000*128 bf16 (12.8 MB)

  prep_weights<<<80, 256, 0, stream>>>(W1, W2, W1t, W2t);
  prep_x<<<6250, 256, 0, stream>>>(x, xb);       // 6250*256*4 = 6.4M elems exactly
  edge_mlp<<<NT2, 256, 0, stream>>>(xb, ei, W1t, W2t, b1, b2, out);
}